// Round 1
// baseline (103.062 us; speedup 1.0000x reference)
//
#include <hip/hip_runtime.h>
#include <math.h>

// N = 2^22, 22 stages of real-butterfly + magnitude (|.| after every stage —
// stage order fixed, NOT commutable like a true FFT).
// Stage s (m=2^s) pairs (p, p+m/2), twiddle fraction r = (p mod m/2)/m revolutions:
//   out_e = sqrt((e + c*o)^2 + (s*o)^2), out_o = sqrt((e - c*o)^2 + (s*o)^2).
//
// P: tiled bitrev permute (64x65 LDS tile) + stages 1-3 (constant twiddles).
// A: stages 4-13 in contiguous 8192-chunks: LDS stage-in (float4 coalesced) ->
//    radix-32 (stages 4-8, stride-8 comb from LDS) -> radix-32 (9-13) -> coalesced store.
// B: stages 14-22 over 512-elem stride-8192 combs: LDS stage-in (float4 along low,
//    1KB/instr) -> radix-32 (14-18) -> 2x radix-16 (19-22) -> LDS stage-out (float4).
//
// R1 changes (this session):
//  * launch_bounds relaxed: A/B (256,4)->(256,2), P (256,8)->(256,4). Grids give
//    only 2 (resp. 4) resident blocks/CU anyway, so the old bounds bought nothing
//    but capped VGPRs at 128 (64 for P) — spill risk for v[32] + unrolled radix.
//  * B: global accesses now float4 along `low` via LDS bounce (was 4x64B sparse
//    segments per wave instruction). New injective LDS pad addr=20t+li+8*(t>>5):
//    <=2-way banks on all patterns, 16B-aligned for b128.
//  * A: LDS stage-in with dense dwordx4 loads (was 8x32B comb segments); pad
//    addr=q+4*(q>>8), <=2-way on linear/stride-8/stride-256 patterns.
//  * P: x loads vectorized to float4 (16->4 VMEM instr/thread).
//  * Block-staggered issue order on staging loops (decorrelate lockstep combs).
//
// NOTE (prev session R6 post-mortem): do NOT fuse these with cooperative
// grid.sync() — two grid syncs on 8 XCDs cost ~120 us vs ~5 us of dispatch gaps.
//
// All twiddles in a radix group derive from ONE sincos via exact double-angle
// + constant rotations (cos/sin(pi*k/16) table). v_sin/v_cos take REVOLUTIONS.

#define NBITS 22
#define RSQ2 0.70710678118654752440f

__device__ __forceinline__ float hsqrt(float x) { return __builtin_amdgcn_sqrtf(x); }

__device__ __forceinline__ void bf(float& e, float& o, float c, float s) {
    float rp = fmaf(c, o, e);
    float rm = fmaf(-c, o, e);
    float im = s * o;
    float im2 = im * im;
    e = hsqrt(fmaf(rp, rp, im2));
    o = hsqrt(fmaf(rm, rm, im2));
}
__device__ __forceinline__ void bf0(float& e, float& o) {   // twiddle (1,0)
    float a = e + o, b = e - o;
    e = fabsf(a); o = fabsf(b);
}
__device__ __forceinline__ void bfq(float& e, float& o) {   // twiddle (0,1)
    float h = hsqrt(fmaf(e, e, o * o));
    e = h; o = h;
}

// Rotation constants: KC[k]=cos(pi*k/16), KS[k]=sin(pi*k/16) (offset k/32 rev).
__device__ __constant__ float KC[16] = {
    1.f, 0.980785280f, 0.923879533f, 0.831469612f, 0.707106781f, 0.555570233f,
    0.382683432f, 0.195090322f, 0.f, -0.195090322f, -0.382683432f, -0.555570233f,
    -0.707106781f, -0.831469612f, -0.923879533f, -0.980785280f };
__device__ __constant__ float KS[16] = {
    0.f, 0.195090322f, 0.382683432f, 0.555570233f, 0.707106781f, 0.831469612f,
    0.923879533f, 0.980785280f, 1.f, 0.980785280f, 0.923879533f, 0.831469612f,
    0.707106781f, 0.555570233f, 0.382683432f, 0.195090322f };

// radix-2^L (L<=5) on v[0..2^L), elements at p = P0 + j*H.
// (c,s) = cos/sin of r_base = P0 / (2^L * H) revolutions (LAST sub-stage base).
template <int L>
__device__ __forceinline__ void radixN(float* v, float c, float s) {
    float ca[L], sa[L];
    ca[L - 1] = c; sa[L - 1] = s;
#pragma unroll
    for (int a = L - 1; a > 0; --a) {
        ca[a - 1] = fmaf(-2.f * sa[a], sa[a], 1.f);
        sa[a - 1] = 2.f * sa[a] * ca[a];
    }
#pragma unroll
    for (int a = 0; a < L; ++a) {
        const int half = 1 << a;
#pragma unroll
        for (int d = 0; d < half; ++d) {
            const int k = d << (4 - a);
            float cd = fmaf(ca[a], KC[k], -sa[a] * KS[k]);
            float sd = fmaf(sa[a], KC[k],  ca[a] * KS[k]);
#pragma unroll
            for (int g = d; g < (1 << L); g += 2 * half)
                bf(v[g], v[g + half], cd, sd);
        }
    }
}

// stages 1..3 (twiddles all constant)
__device__ __forceinline__ void radix8z(float v[8]) {
    bf0(v[0], v[1]); bf0(v[2], v[3]); bf0(v[4], v[5]); bf0(v[6], v[7]);
    bf0(v[0], v[2]); bf0(v[4], v[6]);
    bfq(v[1], v[3]); bfq(v[5], v[7]);
    bf0(v[0], v[4]);
    bf(v[1], v[5], RSQ2, RSQ2);
    bfq(v[2], v[6]);
    bf(v[3], v[7], -RSQ2, RSQ2);
}

// LDS pads. apad: injective (strictly monotone); <=2-way banks for linear-quad,
// {lo+8j+256hi}, {t+256j} patterns; keeps 16B alignment for q%4==0.
__device__ __forceinline__ unsigned apad(unsigned q) { return q + 4u * (q >> 8); }
// bpad: slot stride 20 > 15 => injective; banks: 20t%32 carries t0 bits (8*u5p
// in phase 2), +8*(t>>5) carries u5 in phase 1; all patterns <=2-way; t%... all
// terms %4==0 with li=4*lq => 16B aligned for b128.
__device__ __forceinline__ unsigned bpad(unsigned t, unsigned li) {
    return 20u * t + li + 8u * (t >> 5);
}

// ---------------- Kernel P: bitrev permute + stages 1..3 ----------------
// p = hi11*2048 + lo11; brev22(p) = brev11(lo11)*2048 + brev11(hi11).
__global__ __launch_bounds__(256, 4) void fft_perm(const float* __restrict__ x,
                                                   float* __restrict__ y) {
    __shared__ float lds[64 * 65];
    const unsigned tid = threadIdx.x;
    const unsigned C0 = (blockIdx.x & 31) * 64;
    const unsigned B0 = (blockIdx.x >> 5) * 64;
    const unsigned qi = tid & 15, rr = tid >> 4;

    // float4 loads: per instr 4 rows x 256B. LDS scalar writes are <=2-way
    // (bank = rr + 4*qi + i + 16*(k&1), 32 distinct x2).
#pragma unroll
    for (int k = 0; k < 4; ++k) {
        unsigned r = rr + 16u * k;
        unsigned a = __brev(C0 + r) >> (32 - 11);
        float4 f = *(const float4*)(x + a * 2048u + B0 + 4u * qi);
        float* p = &lds[r * 65u + 4u * qi];
        p[0] = f.x; p[1] = f.y; p[2] = f.z; p[3] = f.w;
    }
    __syncthreads();

    float v[8];
#pragma unroll
    for (int q = 0; q < 2; ++q) {
        unsigned task = tid + 256u * q;
        unsigned c = task >> 3, grp = task & 7;
#pragma unroll
        for (int j = 0; j < 8; ++j) v[j] = lds[(grp * 8u + j) * 65u + c];
        radix8z(v);
        unsigned pr = __brev(B0 + c) >> (32 - 11);
        float* dst = y + pr * 2048u + C0 + grp * 8u;
        *(float4*)(dst)     = make_float4(v[0], v[1], v[2], v[3]);
        *(float4*)(dst + 4) = make_float4(v[4], v[5], v[6], v[7]);
    }
}

// ---------------- Kernel A: stages 4..13 ----------------
__global__ __launch_bounds__(256, 2) void fft_low(float* __restrict__ y) {
    __shared__ float lds[8316];                   // apad(8191) = 8315
    const unsigned t = threadIdx.x;               // 0..255
    const unsigned base = blockIdx.x * 8192u;
    float v[32];

    // stage-in: dense dwordx4 (4KB/wave-instr), block-staggered issue order
    {
        const float4* __restrict__ src4 = (const float4*)(y + base);
#pragma unroll
        for (int k = 0; k < 8; ++k) {
            unsigned kk = ((unsigned)k + blockIdx.x) & 7u;
            float4 f = src4[t + 256u * kk];
            *(float4*)&lds[apad(4u * (t + 256u * kk))] = f;
        }
    }
    __syncthreads();

    // phase 1: stages 4..8 on {lo + 8j + 256hi} (from LDS, <=2-way banks)
    const unsigned lo = t & 7, hi = t >> 3;       // hi 0..31
    {
#pragma unroll
        for (int j = 0; j < 32; ++j) v[j] = lds[apad(lo + 8u * j + 256u * hi)];
        float r = (float)lo * (1.f / 256.f);      // r_base = P0/(32*8)
        radixN<5>(v, __builtin_amdgcn_cosf(r), __builtin_amdgcn_sinf(r));
#pragma unroll
        for (int j = 0; j < 32; ++j) lds[apad(lo + 8u * j + 256u * hi)] = v[j];
    }
    __syncthreads();

    // phase 2: stages 9..13 on {t + 256j}, store coalesced (256B/instr dense)
    {
#pragma unroll
        for (int j = 0; j < 32; ++j) v[j] = lds[apad(t + 256u * j)];
        float r = (float)t * (1.f / 8192.f);      // r_base = P0/(32*256)
        radixN<5>(v, __builtin_amdgcn_cosf(r), __builtin_amdgcn_sinf(r));
        float* dst = y + base + t;
#pragma unroll
        for (int j = 0; j < 32; ++j) {
            unsigned jj = ((unsigned)j + blockIdx.x) & 31u;
            dst[256u * jj] = v[jj];
        }
    }
}

// ---------------- Kernel B: stages 14..22 ----------------
// 16 lows x 512 t (stride 8192). Global I/O via LDS bounce with float4 along
// low: per wave-instr 16 t-rows x 64B = 1KB dense (was 4x64B sparse).
__global__ __launch_bounds__(256, 2) void fft_high(float* __restrict__ y) {
    __shared__ float lds[10356];                  // bpad(511,15) = 10355
    const unsigned tt = threadIdx.x;
    const unsigned low0 = blockIdx.x * 16u;
    float4* __restrict__ Y4 = (float4*)y;
    const unsigned lq = tt & 3, tv = tt >> 2;     // tv 0..63
    float v[32];

    // stage-in
#pragma unroll
    for (int k = 0; k < 8; ++k) {
        unsigned t = tv + 64u * (((unsigned)k + blockIdx.x) & 7u);
        float4 f = Y4[(low0 >> 2) + lq + 2048u * t];
        *(float4*)&lds[bpad(t, 4u * lq)] = f;
    }
    __syncthreads();

    const unsigned li = tt & 15, u5 = tt >> 4;    // u5 0..15
    // phase 1: stages 14..18 on t = 32*u5 + j
    {
#pragma unroll
        for (int j = 0; j < 32; ++j) v[j] = lds[bpad(32u * u5 + j, li)];
        float r = (float)(low0 + li) * (1.f / 262144.f);  // r_base = low/(32*8192)
        radixN<5>(v, __builtin_amdgcn_cosf(r), __builtin_amdgcn_sinf(r));
#pragma unroll
        for (int j = 0; j < 32; ++j) lds[bpad(32u * u5 + j, li)] = v[j];
    }
    __syncthreads();

    // phase 2: stages 19..22, two radix-16 groups t0 = 2*u5 + b, t = t0 + 32j
    // (b=0 writes even-t, b=1 reads odd-t: disjoint, no sync needed between)
#pragma unroll
    for (int b = 0; b < 2; ++b) {
        const unsigned t0 = 2u * u5 + b;
        float* w = v + 16 * b;
#pragma unroll
        for (int j = 0; j < 16; ++j) w[j] = lds[bpad(t0 + 32u * j, li)];
        float r = ((float)(low0 + li) + 8192.f * (float)t0) * (1.f / 4194304.f);
        radixN<4>(w, __builtin_amdgcn_cosf(r), __builtin_amdgcn_sinf(r));
#pragma unroll
        for (int j = 0; j < 16; ++j) lds[bpad(t0 + 32u * j, li)] = w[j];
    }
    __syncthreads();

    // stage-out
#pragma unroll
    for (int k = 0; k < 8; ++k) {
        unsigned t = tv + 64u * (((unsigned)k + 5u + blockIdx.x) & 7u);
        Y4[(low0 >> 2) + lq + 2048u * t] = *(float4*)&lds[bpad(t, 4u * lq)];
    }
}

extern "C" void kernel_launch(void* const* d_in, const int* in_sizes, int n_in,
                              void* d_out, int out_size, void* d_ws, size_t ws_size,
                              hipStream_t stream) {
    const float* x = (const float*)d_in[0];
    float* out = (float*)d_out;

    fft_perm<<<dim3(1024), dim3(256), 0, stream>>>(x, out);
    fft_low<<<dim3(512), dim3(256), 0, stream>>>(out);
    fft_high<<<dim3(512), dim3(256), 0, stream>>>(out);
}

// Round 2
// 99.905 us; speedup vs baseline: 1.0316x; 1.0316x over previous
//
#include <hip/hip_runtime.h>
#include <math.h>

// N = 2^22, 22 stages of real-butterfly + magnitude (|.| after every stage —
// stage order fixed, NOT commutable like a true FFT).
// Stage s (m=2^s) pairs (p, p+m/2), twiddle fraction r = (p mod m/2)/m revolutions:
//   out_e = sqrt((e + c*o)^2 + (s*o)^2), out_o = sqrt((e - c*o)^2 + (s*o)^2).
//
// R2 theory: R0 (direct strided) and R1 (full LDS-bounce/float4) measured
// IDENTICAL -> access pattern was not the binding constraint. Working set
// (16.8 MB) fits aggregate L2; traffic floor ~16 us; VALU floor ~8 us. The
// shared property of R0/R1 was low occupancy: A/B at 256 thr x 512 blocks =
// 8 waves/CU (25%), 32 elems/thread, long serial chains. R2 halves per-thread
// work (16 elems, 512-thread blocks) -> 16 waves/CU on A/B, 32 on P.
//
// P: tiled bitrev permute (64x65 LDS tile) + stages 1-3. 1024 blk x 512 thr.
// A: stages 4-13 per 8192-chunk: radix-16 (4-7, stride 8, global in) -> LDS ->
//    radix-16 (8-11, stride 128) -> LDS -> radix-4 (12-13, stride 2048, global out).
// B: stages 14-22 per 16-low group: radix-16 (14-17, t-stride 1, global in) ->
//    LDS -> radix-16 (18-21, t-stride 16) -> LDS -> radix-2 (22, global out).
//
// NOTE (prev session): do NOT fuse with cooperative grid.sync() — two grid
// syncs on 8 XCDs cost ~120 us vs ~5 us of dispatch gaps.
//
// radixN twiddle contract (verified per phase): elements p = P0 + j*H, pass
// r_base = P0/(2^L*H); requires P0 = beta + H*2^L*gamma with beta < H (the
// gamma part contributes integer revolutions at every sub-stage).
// v_sin/v_cos take REVOLUTIONS.

#define RSQ2 0.70710678118654752440f

__device__ __forceinline__ float hsqrt(float x) { return __builtin_amdgcn_sqrtf(x); }
__device__ __forceinline__ float cosr(float r) { return __builtin_amdgcn_cosf(r); }
__device__ __forceinline__ float sinr(float r) { return __builtin_amdgcn_sinf(r); }

__device__ __forceinline__ void bf(float& e, float& o, float c, float s) {
    float rp = fmaf(c, o, e);
    float rm = fmaf(-c, o, e);
    float im = s * o;
    float im2 = im * im;
    e = hsqrt(fmaf(rp, rp, im2));
    o = hsqrt(fmaf(rm, rm, im2));
}
__device__ __forceinline__ void bf0(float& e, float& o) {   // twiddle (1,0)
    float a = e + o, b = e - o;
    e = fabsf(a); o = fabsf(b);
}
__device__ __forceinline__ void bfq(float& e, float& o) {   // twiddle (0,1)
    float h = hsqrt(fmaf(e, e, o * o));
    e = h; o = h;
}

// Rotation constants: KC[k]=cos(pi*k/16), KS[k]=sin(pi*k/16) (offset k/32 rev).
__device__ __constant__ float KC[16] = {
    1.f, 0.980785280f, 0.923879533f, 0.831469612f, 0.707106781f, 0.555570233f,
    0.382683432f, 0.195090322f, 0.f, -0.195090322f, -0.382683432f, -0.555570233f,
    -0.707106781f, -0.831469612f, -0.923879533f, -0.980785280f };
__device__ __constant__ float KS[16] = {
    0.f, 0.195090322f, 0.382683432f, 0.555570233f, 0.707106781f, 0.831469612f,
    0.923879533f, 0.980785280f, 1.f, 0.980785280f, 0.923879533f, 0.831469612f,
    0.707106781f, 0.555570233f, 0.382683432f, 0.195090322f };

// radix-2^L (L<=5) on v[0..2^L), elements at p = P0 + j*H.
// (c,s) = cos/sin of r_base = P0 / (2^L * H) revolutions (LAST sub-stage base).
template <int L>
__device__ __forceinline__ void radixN(float* v, float c, float s) {
    float ca[L], sa[L];
    ca[L - 1] = c; sa[L - 1] = s;
#pragma unroll
    for (int a = L - 1; a > 0; --a) {
        ca[a - 1] = fmaf(-2.f * sa[a], sa[a], 1.f);
        sa[a - 1] = 2.f * sa[a] * ca[a];
    }
#pragma unroll
    for (int a = 0; a < L; ++a) {
        const int half = 1 << a;
#pragma unroll
        for (int d = 0; d < half; ++d) {
            const int k = d << (4 - a);
            float cd = fmaf(ca[a], KC[k], -sa[a] * KS[k]);
            float sd = fmaf(sa[a], KC[k],  ca[a] * KS[k]);
#pragma unroll
            for (int g = d; g < (1 << L); g += 2 * half)
                bf(v[g], v[g + half], cd, sd);
        }
    }
}

// stages 1..3 (twiddles all constant)
__device__ __forceinline__ void radix8z(float v[8]) {
    bf0(v[0], v[1]); bf0(v[2], v[3]); bf0(v[4], v[5]); bf0(v[6], v[7]);
    bf0(v[0], v[2]); bf0(v[4], v[6]);
    bfq(v[1], v[3]); bfq(v[5], v[7]);
    bf0(v[0], v[4]);
    bf(v[1], v[5], RSQ2, RSQ2);
    bfq(v[2], v[6]);
    bf(v[3], v[7], -RSQ2, RSQ2);
}

// A pad: scalar LDS ops only, classic q+(q>>5). <=2-way on all three phase
// patterns (ph1 {lo+8j+128h}: bank ~ lo+4h; ph2 {m+128j+2048g}: m 64-consec;
// ph3 {c+2048j}: c 64-consec).
__device__ __forceinline__ unsigned apad(unsigned q) { return q + (q >> 5); }
// B layout: [t][li] slot = 17t + li; scalar ops; 17 mod 32 spreads t0/u
// sub-steps across banks, li covers 16 -> <=2-way on all phase patterns.
__device__ __forceinline__ unsigned bmap(unsigned t, unsigned li) { return t * 17u + li; }

// ---------------- Kernel P: bitrev permute + stages 1..3 ----------------
// p = hi11*2048 + lo11; brev22(p) = brev11(lo11)*2048 + brev11(hi11).
// 512 threads, 8 elems/thread, 1024 blocks -> 4 blk/CU = 32 waves/CU.
__global__ __launch_bounds__(512, 8) void fft_perm(const float* __restrict__ x,
                                                   float* __restrict__ y) {
    __shared__ float lds[64 * 65];
    const unsigned tid = threadIdx.x;
    const unsigned C0 = (blockIdx.x & 31) * 64;
    const unsigned B0 = (blockIdx.x >> 5) * 64;
    const unsigned qi = tid & 15, rr = tid >> 4;   // rr 0..31

#pragma unroll
    for (int k = 0; k < 2; ++k) {
        unsigned r = rr + 32u * k;
        unsigned a = __brev(C0 + r) >> (32 - 11);
        float4 f = *(const float4*)(x + a * 2048u + B0 + 4u * qi);
        float* p = &lds[r * 65u + 4u * qi];
        p[0] = f.x; p[1] = f.y; p[2] = f.z; p[3] = f.w;
    }
    __syncthreads();

    float v[8];
    const unsigned c = tid >> 3, grp = tid & 7;
#pragma unroll
    for (int j = 0; j < 8; ++j) v[j] = lds[(grp * 8u + j) * 65u + c];
    radix8z(v);
    unsigned pr = __brev(B0 + c) >> (32 - 11);
    float* dst = y + pr * 2048u + C0 + grp * 8u;
    *(float4*)(dst)     = make_float4(v[0], v[1], v[2], v[3]);
    *(float4*)(dst + 4) = make_float4(v[4], v[5], v[6], v[7]);
}

// ---------------- Kernel A: stages 4..13 ----------------
// 512 thr x 512 blocks, 16 elems/thread -> 2 blk/CU = 16 waves/CU.
__global__ __launch_bounds__(512, 4) void fft_low(float* __restrict__ y) {
    __shared__ float lds[8447];                    // apad(8191) = 8446
    const unsigned t = threadIdx.x;                // 0..511
    const unsigned base = blockIdx.x * 8192u;
    float v[16];

    // ph1: stages 4-7 on q = lo + 8j + 128h (global in, L2-resident)
    {
        const unsigned lo = t & 7, h = t >> 3;     // h 0..63
        const float* src = y + base + lo + 128u * h;
#pragma unroll
        for (int j = 0; j < 16; ++j) v[j] = src[8u * j];
        float r = (float)lo * (1.f / 128.f);       // r_base = lo/(16*8)
        radixN<4>(v, cosr(r), sinr(r));
#pragma unroll
        for (int j = 0; j < 16; ++j) lds[apad(lo + 8u * j + 128u * h)] = v[j];
    }
    __syncthreads();

    // ph2: stages 8-11 on q = m + 128j + 2048g
    {
        const unsigned m = t & 127, g = t >> 7;    // g 0..3
#pragma unroll
        for (int j = 0; j < 16; ++j) v[j] = lds[apad(m + 128u * j + 2048u * g)];
        float r = (float)m * (1.f / 2048.f);       // r_base = m/(16*128)
        radixN<4>(v, cosr(r), sinr(r));
#pragma unroll
        for (int j = 0; j < 16; ++j) lds[apad(m + 128u * j + 2048u * g)] = v[j];
    }
    __syncthreads();

    // ph3: stages 12-13 on q = c + 2048j, c = t + 512w (global out, 256B dense)
#pragma unroll
    for (int w = 0; w < 4; ++w) {
        const unsigned c = t + 512u * w;
        float u4[4];
#pragma unroll
        for (int j = 0; j < 4; ++j) u4[j] = lds[apad(c + 2048u * j)];
        float r = (float)c * (1.f / 8192.f);       // r_base = c/(4*2048)
        radixN<2>(u4, cosr(r), sinr(r));
#pragma unroll
        for (int j = 0; j < 4; ++j) y[base + c + 2048u * j] = u4[j];
    }
}

// ---------------- Kernel B: stages 14..22 ----------------
// 16 lows x 512 t (p = low + 8192 t). 512 thr x 512 blocks, 16 elems/thread
// -> 2 blk/CU = 16 waves/CU.
__global__ __launch_bounds__(512, 4) void fft_high(float* __restrict__ y) {
    __shared__ float lds[17 * 511 + 16];           // bmap(511,15) = 8702
    const unsigned tt = threadIdx.x;
    const unsigned low0 = blockIdx.x * 16u;
    const unsigned li = tt & 15;
    const float lowf = (float)(low0 + li);
    float v[16];

    // ph1: stages 14-17 on t = 16u + j (global in, 64B segments)
    {
        const unsigned u = tt >> 4;                // 0..31
        const float* src = y + low0 + li + 131072u * u;
#pragma unroll
        for (int j = 0; j < 16; ++j) v[j] = src[8192u * j];
        float r = lowf * (1.f / 131072.f);         // r_base = low/(16*8192)
        radixN<4>(v, cosr(r), sinr(r));
#pragma unroll
        for (int j = 0; j < 16; ++j) lds[bmap(16u * u + j, li)] = v[j];
    }
    __syncthreads();

    // ph2: stages 18-21 on t = t0 + 16j + 256b
    {
        const unsigned idx = tt >> 4;              // 0..31
        const unsigned t0 = idx & 15, b = idx >> 4;
#pragma unroll
        for (int j = 0; j < 16; ++j)
            v[j] = lds[bmap(t0 + 16u * j + 256u * b, li)];
        // r_base = (low + 8192*t0)/(16*131072); the 2^21*b part is integer revs
        float r = fmaf(8192.f, (float)t0, lowf) * (1.f / 2097152.f);
        radixN<4>(v, cosr(r), sinr(r));
#pragma unroll
        for (int j = 0; j < 16; ++j)
            lds[bmap(t0 + 16u * j + 256u * b, li)] = v[j];
    }
    __syncthreads();

    // ph3: stage 22, pairs (tau, tau+256) in t-space (global out, 64B segments)
#pragma unroll
    for (int w = 0; w < 8; ++w) {
        unsigned tau = (tt >> 4) + 32u * w;        // 0..255
        float e = lds[bmap(tau, li)];
        float o = lds[bmap(tau + 256u, li)];
        float r = fmaf(8192.f, (float)tau, lowf) * (1.f / 4194304.f);
        bf(e, o, cosr(r), sinr(r));
        y[low0 + li + 8192u * tau]          = e;
        y[low0 + li + 8192u * (tau + 256u)] = o;
    }
}

extern "C" void kernel_launch(void* const* d_in, const int* in_sizes, int n_in,
                              void* d_out, int out_size, void* d_ws, size_t ws_size,
                              hipStream_t stream) {
    const float* x = (const float*)d_in[0];
    float* out = (float*)d_out;

    fft_perm<<<dim3(1024), dim3(512), 0, stream>>>(x, out);
    fft_low<<<dim3(512), dim3(512), 0, stream>>>(out);
    fft_high<<<dim3(512), dim3(512), 0, stream>>>(out);
}